// Round 16
// baseline (94.656 us; speedup 1.0000x reference)
//
#include <hip/hip_runtime.h>
#include <cstdint>
#include <cstddef>

// ---------------------------------------------------------------------------
// AFMADE block, incremental-exact formulation. D=16, H=1024, B=2048.
// Degree-sorted space: y[d] final after step d; h0/h1 degree-groups computed
// once. Per step s: h1 group s-1 (K=Lb(s)) -> ML += @W2g -> mu/lv[s] ->
// y[s] -> h0 group s. R16: 256 blocks x 256 threads, 8 rows/block,
// 2 blocks/CU (independent scan-chains overlap barriers/serial tails).
// 4 waves = (net, kq 2-way K-split); R14's proven 2-slot static register
// pipeline (A/B parity, next-step iter-0 prefetch at last position).
// MFMA M=16 vs 8 rows: A-rows aliased (lr&7), C-rows 8-15 discarded.
// ---------------------------------------------------------------------------

#define Dd 16
#define Hh 1024
#define Bb 2048
#define EPSV 1e-12f

typedef unsigned short u16;
typedef __attribute__((ext_vector_type(4))) float f32x4;
typedef __attribute__((ext_vector_type(8))) short s16x8;
typedef __attribute__((ext_vector_type(4))) u16 u16x4;
typedef __attribute__((ext_vector_type(8))) u16 u16x8;

__device__ __forceinline__ u16 f2bf(float f) {
  union { float f; unsigned u; } v; v.f = f;
  unsigned u = v.u;
  unsigned r = (u + 0x7fffu + ((u >> 16) & 1u)) >> 16;  // RNE
  return (u16)r;
}
__device__ __forceinline__ float elu(float a) {
  return a > 0.f ? a : __expf(a) - 1.f;
}
// LDS-visibility barrier that does NOT drain vmcnt (keeps prefetches alive).
__device__ __forceinline__ void barrier_lds() {
  asm volatile("s_waitcnt lgkmcnt(0)" ::: "memory");
  __builtin_amdgcn_s_barrier();
}

// Degree-sort permutation: group g = j%15; groups 0..3 have 69, 4..14 have 68.
__device__ __forceinline__ int p_of(int i) {
  if (i < 276) { int g = i / 69, q = i - g * 69; return g + 15 * q; }
  int r = i - 276; int g = 4 + r / 68, q = r - (g - 4) * 68;
  return g + 15 * q;
}
__device__ __forceinline__ int g_of(int i) {
  return (i < 276) ? (i / 69) : (4 + (i - 276) / 68);
}
__device__ __forceinline__ int lb_of(int g) {            // prefix length
  return (g <= 4) ? 69 * g : 276 + 68 * (g - 4);
}
__device__ __forceinline__ int sz_of(int g) { return (g < 4) ? 69 : 68; }

// Padded layouts (all pads baked ZERO):
//  W1p[net][15][80][1024] bf16 (linear, input to prep_w1f)
//  W1f[net][15][16 kt][5 nf][2 kk][64 lane][8] bf16 (fragment order)
//  W2p[net][15][16][104] bf16, W0p[net][15][80][32] bf16,
//  b1p/b0p[net][15][80] f32.
#define W1P_NET (15 * 80 * 1024)
#define W2P_NET (15 * 16 * 104)
#define W0P_NET (15 * 80 * 32)

// --------------------------- prep (one dispatch, 600 blocks) ---------------
__global__ __launch_bounds__(256) void prep_all(
    const float* __restrict__ mu_v0, const float* __restrict__ mu_g0,
    const float* __restrict__ mu_b0,
    const float* __restrict__ mu_v1, const float* __restrict__ mu_g1,
    const float* __restrict__ mu_b1,
    const float* __restrict__ mu_v2, const float* __restrict__ mu_g2,
    const float* __restrict__ lv_v0, const float* __restrict__ lv_g0,
    const float* __restrict__ lv_b0,
    const float* __restrict__ lv_v1, const float* __restrict__ lv_g1,
    const float* __restrict__ lv_b1,
    const float* __restrict__ lv_v2, const float* __restrict__ lv_g2,
    u16* __restrict__ W1p, u16* __restrict__ W2p, u16* __restrict__ W0p,
    float* __restrict__ b1p, float* __restrict__ b0p) {
  int bid = blockIdx.x, tid = threadIdx.x;
  int l = tid & 63, w = tid >> 6;

  {  // W1p: one wave per padded row; wid = net*1200 + g*80 + u
    int wid = bid * 4 + w;                 // 0..2399
    int net = wid / 1200, rem = wid % 1200;
    int g = rem / 80, u = rem % 80;
    u16* o = W1p + (size_t)wid * 1024;
    if (u < sz_of(g)) {
      int j = p_of(lb_of(g) + u);
      const float* v = (net ? lv_v1 : mu_v1) + (size_t)j * Hh;
      float val[4][4]; float ss = 0.f;
      for (int ii = 0; ii < 4; ++ii)
        for (int t = 0; t < 4; ++t) {
          int kp = ii * 256 + 4 * l + t;
          float xx = v[p_of(kp)];
          val[ii][t] = xx; ss += xx * xx;
        }
      for (int s = 32; s; s >>= 1) ss += __shfl_xor(ss, s);
      float sc = ((net ? lv_g1 : mu_g1)[j]) * rsqrtf(ss);
      for (int ii = 0; ii < 4; ++ii) {
        int k0 = ii * 256 + 4 * l;
        u16x4 wv;
        for (int t = 0; t < 4; ++t)
          wv[t] = f2bf((g >= g_of(k0 + t)) ? sc * val[ii][t] : 0.f);
        *(u16x4*)(o + k0) = wv;
      }
    } else {
      u16x4 z = {0, 0, 0, 0};
      for (int ii = 0; ii < 4; ++ii) *(u16x4*)(o + ii * 256 + 4 * l) = z;
    }
  }

  if (bid < 8) {  // W2p: one wave per (net, out-row)
    int wid2 = bid * 4 + w;                // 0..31
    int nn = wid2 >> 4, oi = wid2 & 15;
    const float* v = (nn ? lv_v2 : mu_v2) + (size_t)oi * Hh;
    float ss = 0.f;
    for (int ii = 0; ii < 4; ++ii) {
      f32x4 vv = *(const f32x4*)(v + ii * 256 + 4 * l);
      ss += vv[0]*vv[0] + vv[1]*vv[1] + vv[2]*vv[2] + vv[3]*vv[3];
    }
    for (int s = 32; s; s >>= 1) ss += __shfl_xor(ss, s);
    float sc = ((nn ? lv_g2 : mu_g2)[oi]) * rsqrtf(ss);
    for (int e = l; e < 15 * 104; e += 64) {
      int g = e / 104, u = e % 104;
      float val = 0.f;
      if (u < sz_of(g) && oi > g) val = sc * v[p_of(lb_of(g) + u)];
      W2p[nn * W2P_NET + g * (16 * 104) + oi * 104 + u] = f2bf(val);
    }
  }

  if (bid >= 8 && bid < 18) {  // W0p + b0p + b1p: one thread per padded unit
    int idx = (bid - 8) * 256 + tid;       // 0..2559
    if (idx < 2400) {
      int nn = idx / 1200, rem = idx % 1200;
      int g = rem / 80, u = rem % 80;
      u16* orow = W0p + nn * W0P_NET + g * (80 * 32) + u * 32;
      if (u < sz_of(g)) {
        int j = p_of(lb_of(g) + u);
        const float* v = (nn ? lv_v0 : mu_v0) + j * Dd;
        float vv[16]; float ss = 0.f;
        for (int k = 0; k < 16; ++k) { vv[k] = v[k]; ss += vv[k] * vv[k]; }
        float sc = ((nn ? lv_g0 : mu_g0)[j]) * rsqrtf(ss);
        for (int k = 0; k < 16; ++k)
          orow[k] = f2bf((g >= k) ? sc * vv[k] : 0.f);
        for (int k = 16; k < 32; ++k) orow[k] = 0;
        b0p[nn * 1200 + g * 80 + u] = (nn ? lv_b0 : mu_b0)[j];
        b1p[nn * 1200 + g * 80 + u] = (nn ? lv_b1 : mu_b1)[j];
      } else {
        for (int k = 0; k < 32; ++k) orow[k] = 0;
        b0p[nn * 1200 + g * 80 + u] = 0.f;
        b1p[nn * 1200 + g * 80 + u] = 0.f;
      }
    }
  }
}

// --------------------------- W1 fragment transform -------------------------
__global__ __launch_bounds__(256) void prep_w1f(
    const u16* __restrict__ W1p, u16* __restrict__ W1f) {
  int t = blockIdx.x * 4 + (threadIdx.x >> 6);   // 0..479
  int l = threadIdx.x & 63;
  int net = t / 240, rem = t % 240;
  int g = rem >> 4, kt = rem & 15;
  if (kt >= ((lb_of(g + 1) + 63) >> 6)) return;  // unused kt slice
  const u16* src = W1p + (size_t)(net * 1200 + g * 80) * 1024;
  u16* dst = W1f + ((size_t)((net * 15 + g) * 16 + kt) * 10) * 512;
  for (int nf = 0; nf < 5; ++nf)
    for (int kk = 0; kk < 2; ++kk) {
      int u = nf * 16 + (l & 15);
      int k = kt * 64 + kk * 32 + ((l >> 4) << 3);
      u16x8 v = *(const u16x8*)(src + (size_t)u * 1024 + k);
      *(u16x8*)(dst + (size_t)(nf * 2 + kk) * 512 + l * 8) = v;
    }
}

// fragment load / mfma helper macros (all register indices compile-time)
#define LOADF(DST, BASE, KT)                                                \
  {                                                                         \
    const u16* fp_ = (BASE) + (size_t)(KT) * 5120;                          \
    _Pragma("unroll") for (int nf_ = 0; nf_ < 5; ++nf_)                     \
      _Pragma("unroll") for (int kk_ = 0; kk_ < 2; ++kk_)                   \
        DST[nf_][kk_] = *(const s16x8*)(fp_ + (nf_ * 2 + kk_) * 512);       \
  }
#define MFMAI(SLOT, KT)                                                     \
  {                                                                         \
    s16x8 a0_ = *(const s16x8*)(&h0L[net][lr & 7][(KT) * 64 + lk * 8]);     \
    s16x8 a1_ = *(const s16x8*)(&h0L[net][lr & 7][(KT) * 64 + 32 + lk * 8]);\
    _Pragma("unroll") for (int nf_ = 0; nf_ < 5; ++nf_) {                   \
      hacc[nf_] = __builtin_amdgcn_mfma_f32_16x16x32_bf16(                  \
          a0_, SLOT[nf_][0], hacc[nf_], 0, 0, 0);                           \
      hacc[nf_] = __builtin_amdgcn_mfma_f32_16x16x32_bf16(                  \
          a1_, SLOT[nf_][1], hacc[nf_], 0, 0, 0);                           \
    }                                                                       \
  }

// --------------------------- main (one dispatch, 256 blocks) ---------------
// Block owns 8 rows; 4 waves = (net, kq 2-way K-split); 2 blocks/CU.
__global__ __launch_bounds__(256, 2) void afmade_main(
    const u16* __restrict__ W1f, const u16* __restrict__ W2p,
    const u16* __restrict__ W0p,
    const float* __restrict__ b1p, const float* __restrict__ b0p,
    const float* __restrict__ b2_mu, const float* __restrict__ b2_lv,
    const float* __restrict__ x, float* __restrict__ out) {
  __shared__ u16 h0L[2][8][1040];         // 33.3 KB (stride 2080B)
  __shared__ float sPart[2][2][8][80];    // 10.2 KB
  __shared__ u16 sH1[2][8][104];          // cols 80..103 stay zero
  __shared__ u16 yb[8][40];               // cols 16..39 stay zero
  __shared__ float sX[8][16];
  __shared__ float sB1L[2400];
  __shared__ float sB0L[2400];
  __shared__ float sB2[2][16];
  __shared__ float sMLex[2][16];
  __shared__ float sLsum[8];

  const int tid = threadIdx.x;
  const int l = tid & 63, w = tid >> 6;   // 4 waves
  const int net = w >> 1, kq = w & 1;
  const int lr = l & 15, lk = l >> 4;
  const int b0g = blockIdx.x * 8;

  {  // zero-init LDS state (zeros make masked-weight products exact)
    u16x8 z = {0, 0, 0, 0, 0, 0, 0, 0};
    for (int e = tid; e < 2080; e += 256) ((u16x8*)h0L)[e] = z;
    for (int e = tid; e < 208; e += 256) ((u16x8*)sH1)[e] = z;
    if (tid < 40) ((u16x8*)yb)[tid] = z;
  }
  if (tid < 128) sX[tid >> 4][tid & 15] =
      x[(size_t)(b0g + (tid >> 4)) * 16 + (tid & 15)];
  for (int e = tid; e < 2400; e += 256) { sB1L[e] = b1p[e]; sB0L[e] = b0p[e]; }
  if (tid < 16) sB2[0][tid] = b2_mu[tid];
  else if (tid < 32) sB2[1][tid - 16] = b2_lv[tid - 16];
  else if (tid < 40) sLsum[tid - 32] = 0.f;
  f32x4 mlacc0 = {0.f, 0.f, 0.f, 0.f};   // wave 0: mu net ML
  f32x4 mlacc1 = {0.f, 0.f, 0.f, 0.f};   // wave 0: lv net ML

  // 2-slot static register pipeline for W1 B-frags (R14-proven parity).
  s16x8 bfA[5][2], bfB[5][2];
  {  // prologue: step-1 (g=0, ktn=2) iter-0 -> A
    const u16* base1 = W1f + ((size_t)((net * 15 + 0) * 16) * 10) * 512 +
                       (size_t)l * 8;
    if (kq < 2) LOADF(bfA, base1, kq);
  }
  __syncthreads();

  for (int s = 0; s < 16; ++s) {
    // W0 frag prefetch (consumed after bar3); nf = kq, kq+2, kq+4
    s16x8 w0pre0, w0pre1, w0pre2;
    if (s < 15) {
      const u16* W0g = W0p + net * W0P_NET + s * (80 * 32);
      w0pre0 = *(const s16x8*)(W0g + (kq * 16 + lr) * 32 + lk * 8);
      w0pre1 = *(const s16x8*)(W0g + ((kq + 2) * 16 + lr) * 32 + lk * 8);
      if (kq == 0)
        w0pre2 = *(const s16x8*)(W0g + (64 + lr) * 32 + lk * 8);
    }

    if (s > 0) {
      const int g = s - 1;
      const int ktn = (lb_of(s) + 63) >> 6;
      const int ktnN = (s < 15) ? ((lb_of(s + 1) + 63) >> 6) : 0;
      const u16* baseg = W1f + ((size_t)((net * 15 + g) * 16) * 10) * 512 +
                         (size_t)l * 8;
      const u16* basen = W1f + ((size_t)((net * 15 + s) * 16) * 10) * 512 +
                         (size_t)l * 8;
      // wave 0: issue both nets' W2 frag loads early (used after bar2)
      s16x8 w2f[6];
      if (w == 0) {
#pragma unroll
        for (int c = 0; c < 3; ++c) {
          w2f[c] = *(const s16x8*)(W2p + g * (16 * 104) + lr * 104 +
                                   c * 32 + lk * 8);
          w2f[3 + c] = *(const s16x8*)(W2p + W2P_NET + g * (16 * 104) +
                                       lr * 104 + c * 32 + lk * 8);
        }
      }
      // GEMM: 8 static positions, kt = kq + 2*i, slots alternate A/B;
      // position 7 prefetches NEXT step's iter-0 into A.
      f32x4 hacc[5] = {};
      if (kq + 2 < ktn)  LOADF(bfB, baseg, kq + 2);
      if (kq < ktn)      MFMAI(bfA, kq);
      if (kq + 4 < ktn)  LOADF(bfA, baseg, kq + 4);
      if (kq + 2 < ktn)  MFMAI(bfB, kq + 2);
      if (kq + 6 < ktn)  LOADF(bfB, baseg, kq + 6);
      if (kq + 4 < ktn)  MFMAI(bfA, kq + 4);
      if (kq + 8 < ktn)  LOADF(bfA, baseg, kq + 8);
      if (kq + 6 < ktn)  MFMAI(bfB, kq + 6);
      if (kq + 10 < ktn) LOADF(bfB, baseg, kq + 10);
      if (kq + 8 < ktn)  MFMAI(bfA, kq + 8);
      if (kq + 12 < ktn) LOADF(bfA, baseg, kq + 12);
      if (kq + 10 < ktn) MFMAI(bfB, kq + 10);
      if (kq + 14 < ktn) LOADF(bfB, baseg, kq + 14);
      if (kq + 12 < ktn) MFMAI(bfA, kq + 12);
      if (kq + 14 < ktn) MFMAI(bfB, kq + 14);
      // write partials (valid C-rows 0..7 only)
#pragma unroll
      for (int nf = 0; nf < 5; ++nf)
#pragma unroll
        for (int reg = 0; reg < 4; ++reg) {
          int row = lk * 4 + reg;
          if (row < 8) sPart[net][kq][row][nf * 16 + lr] = hacc[nf][reg];
        }
      // tail prefetch: next step's iter-0 lands under the step tail
      if (s < 15 && kq < ktnN) LOADF(bfA, basen, kq);
      barrier_lds();                       // bar1 (sPart visible)
      // reduce 2 partials + bias + elu -> sH1 (div-free, 5/thread)
      {
        const int nn = tid >> 7;
        const int rr = (tid >> 4) & 7;
        const int u0 = tid & 15;
#pragma unroll
        for (int c = 0; c < 5; ++c) {
          int uu = c * 16 + u0;
          float v = sPart[nn][0][rr][uu] + sPart[nn][1][rr][uu] +
                    sB1L[nn * 1200 + g * 80 + uu];
          sH1[nn][rr][uu] = f2bf(elu(v));
        }
      }
      barrier_lds();                       // bar2 (sH1 visible)
      // ML += h1grp @ W2g^T for BOTH nets in wave 0 (K=96; pads zero)
      if (w == 0) {
#pragma unroll
        for (int c = 0; c < 3; ++c) {
          s16x8 a0 = *(const s16x8*)(&sH1[0][lr & 7][c * 32 + lk * 8]);
          mlacc0 = __builtin_amdgcn_mfma_f32_16x16x32_bf16(
              a0, w2f[c], mlacc0, 0, 0, 0);
          s16x8 a1v = *(const s16x8*)(&sH1[1][lr & 7][c * 32 + lk * 8]);
          mlacc1 = __builtin_amdgcn_mfma_f32_16x16x32_bf16(
              a1v, w2f[3 + c], mlacc1, 0, 0, 0);
        }
      }
    }
    // y update (wave 0, lanes lr==s hold ML column s; valid rows < 8)
    if (w == 0 && lr == s) {
#pragma unroll
      for (int reg = 0; reg < 4; ++reg) {
        int r = lk * 4 + reg;
        if (r < 8) {
          float mu = mlacc0[reg] + sB2[0][s];
          float lv = mlacc1[reg] + sB2[1][s];
          float ls = 0.5f * lv;
          float yv = (sX[r][s] - mu) / (__expf(ls) + EPSV);
          out[(size_t)(b0g + r) * 16 + s] = yv;
          yb[r][s] = f2bf(yv);
          float ns = sLsum[r] + ls;
          sLsum[r] = ns;
          if (s == 15) out[Bb * 16 + b0g + r] = ns;
        }
      }
    }
    barrier_lds();                         // bar3 (yb visible)
    if (s < 15) {
      // h0 group s = elu(y @ W0g^T + b0) -> h0L; nf = kq, kq+2, kq+4
      const int LbS = lb_of(s), szS = sz_of(s);
      s16x8 yfrag = *(const s16x8*)(&yb[lr & 7][lk * 8]);
      {
        int unit = kq * 16 + lr;
        f32x4 h = __builtin_amdgcn_mfma_f32_16x16x32_bf16(
            yfrag, w0pre0, (f32x4){0.f, 0.f, 0.f, 0.f}, 0, 0, 0);
        if (unit < szS) {
          float bias = sB0L[net * 1200 + s * 80 + unit];
#pragma unroll
          for (int reg = 0; reg < 4; ++reg) {
            int row = lk * 4 + reg;
            if (row < 8) h0L[net][row][LbS + unit] = f2bf(elu(h[reg] + bias));
          }
        }
      }
      {
        int unit = (kq + 2) * 16 + lr;
        f32x4 h = __builtin_amdgcn_mfma_f32_16x16x32_bf16(
            yfrag, w0pre1, (f32x4){0.f, 0.f, 0.f, 0.f}, 0, 0, 0);
        if (unit < szS) {
          float bias = sB0L[net * 1200 + s * 80 + unit];
#pragma unroll
          for (int reg = 0; reg < 4; ++reg) {
            int row = lk * 4 + reg;
            if (row < 8) h0L[net][row][LbS + unit] = f2bf(elu(h[reg] + bias));
          }
        }
      }
      if (kq == 0) {
        int unit = 64 + lr;
        f32x4 h = __builtin_amdgcn_mfma_f32_16x16x32_bf16(
            yfrag, w0pre2, (f32x4){0.f, 0.f, 0.f, 0.f}, 0, 0, 0);
        if (unit < szS) {
          float bias = sB0L[net * 1200 + s * 80 + unit];
#pragma unroll
          for (int reg = 0; reg < 4; ++reg) {
            int row = lk * 4 + reg;
            if (row < 8) h0L[net][row][LbS + unit] = f2bf(elu(h[reg] + bias));
          }
        }
      }
      barrier_lds();                       // bar4 (h0L stable)
    }
  }
}

// --------------------------- launch ----------------------------------------

extern "C" void kernel_launch(void* const* d_in, const int* in_sizes, int n_in,
                              void* d_out, int out_size, void* d_ws, size_t ws_size,
                              hipStream_t stream) {
  const float* x     = (const float*)d_in[0];
  const float* mu_v0 = (const float*)d_in[1];
  const float* mu_g0 = (const float*)d_in[2];
  const float* mu_b0 = (const float*)d_in[3];
  const float* mu_v1 = (const float*)d_in[4];
  const float* mu_g1 = (const float*)d_in[5];
  const float* mu_b1 = (const float*)d_in[6];
  const float* mu_v2 = (const float*)d_in[7];
  const float* mu_g2 = (const float*)d_in[8];
  const float* mu_b2 = (const float*)d_in[9];
  const float* lv_v0 = (const float*)d_in[10];
  const float* lv_g0 = (const float*)d_in[11];
  const float* lv_b0 = (const float*)d_in[12];
  const float* lv_v1 = (const float*)d_in[13];
  const float* lv_g1 = (const float*)d_in[14];
  const float* lv_b1 = (const float*)d_in[15];
  const float* lv_v2 = (const float*)d_in[16];
  const float* lv_g2 = (const float*)d_in[17];
  const float* lv_b2 = (const float*)d_in[18];

  char* ws = (char*)d_ws;
  u16*   W1p = (u16*)(ws);                       // 4,915,200 B
  u16*   W2p = (u16*)(ws + 4915200);             //    99,840 B
  u16*   W0p = (u16*)(ws + 5015040);             //   153,600 B
  float* b1p = (float*)(ws + 5168640);           //     9,600 B
  float* b0p = (float*)(ws + 5178240);           //     9,600 B
  u16*   W1f = (u16*)(ws + 5187840);             // 4,915,200 B

  prep_all<<<600, 256, 0, stream>>>(
      mu_v0, mu_g0, mu_b0, mu_v1, mu_g1, mu_b1, mu_v2, mu_g2,
      lv_v0, lv_g0, lv_b0, lv_v1, lv_g1, lv_b1, lv_v2, lv_g2,
      W1p, W2p, W0p, b1p, b0p);
  prep_w1f<<<120, 256, 0, stream>>>(W1p, W1f);

  afmade_main<<<256, 256, 0, stream>>>(W1f, W2p, W0p, b1p, b0p,
                                       mu_b2, lv_b2, x, (float*)d_out);
}

// Round 17
// 76.239 us; speedup vs baseline: 1.2416x; 1.2416x over previous
//
#include <hip/hip_runtime.h>
#include <cstdint>
#include <cstddef>

// ---------------------------------------------------------------------------
// AFMADE block, incremental-exact formulation. D=16, H=1024, B=2048.
// Degree-sorted space: y[d] final after step d; h0/h1 degree-groups computed
// once. Per step s: h1 group s-1 (K=Lb(s)) -> ML += @W2g -> mu/lv[s] ->
// y[s] -> h0 group s. Block owns 16 rows; 8 waves = (net, kq 4-way K-split).
// R17 = R14 (proven 75us structure: 2-slot static register pipeline, next-
// step iter-0 tail prefetch, lgkmcnt-only barriers) +
//  (a) ML/y computed REDUNDANTLY by all 8 waves -> bar3 deleted, no wave-0
//      serialization (yb identical-value LDS race is benign; sLsum/out stay
//      wave-0-only to avoid RMW races);
//  (b) W1f fragment layout baked directly in prep_all (W1p + prep_w1f
//      dispatch removed). 2 dispatches total.
// ---------------------------------------------------------------------------

#define Dd 16
#define Hh 1024
#define Bb 2048
#define EPSV 1e-12f

typedef unsigned short u16;
typedef __attribute__((ext_vector_type(4))) float f32x4;
typedef __attribute__((ext_vector_type(8))) short s16x8;
typedef __attribute__((ext_vector_type(4))) u16 u16x4;
typedef __attribute__((ext_vector_type(8))) u16 u16x8;

__device__ __forceinline__ u16 f2bf(float f) {
  union { float f; unsigned u; } v; v.f = f;
  unsigned u = v.u;
  unsigned r = (u + 0x7fffu + ((u >> 16) & 1u)) >> 16;  // RNE
  return (u16)r;
}
__device__ __forceinline__ float elu(float a) {
  return a > 0.f ? a : __expf(a) - 1.f;
}
// LDS-visibility barrier that does NOT drain vmcnt (keeps prefetches alive).
__device__ __forceinline__ void barrier_lds() {
  asm volatile("s_waitcnt lgkmcnt(0)" ::: "memory");
  __builtin_amdgcn_s_barrier();
}

// Degree-sort permutation: group g = j%15; groups 0..3 have 69, 4..14 have 68.
__device__ __forceinline__ int p_of(int i) {
  if (i < 276) { int g = i / 69, q = i - g * 69; return g + 15 * q; }
  int r = i - 276; int g = 4 + r / 68, q = r - (g - 4) * 68;
  return g + 15 * q;
}
__device__ __forceinline__ int g_of(int i) {
  return (i < 276) ? (i / 69) : (4 + (i - 276) / 68);
}
__device__ __forceinline__ int lb_of(int g) {            // prefix length
  return (g <= 4) ? 69 * g : 276 + 68 * (g - 4);
}
__device__ __forceinline__ int sz_of(int g) { return (g < 4) ? 69 : 68; }

// Padded layouts (all pads baked ZERO):
//  W1f[net][15][16 kt][5 nf][2 kk][64 lane][8] bf16 (fragment order)
//  W2p[net][15][16][104] bf16, W0p[net][15][80][32] bf16,
//  b1p/b0p[net][15][80] f32.
#define W2P_NET (15 * 16 * 104)
#define W0P_NET (15 * 80 * 32)

// --------------------------- prep (one dispatch, 600 blocks) ---------------
// W1f written directly in MFMA-fragment order (scattered aligned 8B stores).
__global__ __launch_bounds__(256) void prep_all(
    const float* __restrict__ mu_v0, const float* __restrict__ mu_g0,
    const float* __restrict__ mu_b0,
    const float* __restrict__ mu_v1, const float* __restrict__ mu_g1,
    const float* __restrict__ mu_b1,
    const float* __restrict__ mu_v2, const float* __restrict__ mu_g2,
    const float* __restrict__ lv_v0, const float* __restrict__ lv_g0,
    const float* __restrict__ lv_b0,
    const float* __restrict__ lv_v1, const float* __restrict__ lv_g1,
    const float* __restrict__ lv_b1,
    const float* __restrict__ lv_v2, const float* __restrict__ lv_g2,
    u16* __restrict__ W1f, u16* __restrict__ W2p, u16* __restrict__ W0p,
    float* __restrict__ b1p, float* __restrict__ b0p) {
  int bid = blockIdx.x, tid = threadIdx.x;
  int l = tid & 63, w = tid >> 6;

  {  // W1f: one wave per padded row; wid = net*1200 + g*80 + u
    int wid = bid * 4 + w;                 // 0..2399
    int net = wid / 1200, rem = wid % 1200;
    int g = rem / 80, u = rem % 80;
    u16* dstb = W1f + ((size_t)((net * 15 + g) * 16) * 10) * 512;
    const int nf = u >> 4, lane16 = u & 15;
    if (u < sz_of(g)) {
      int j = p_of(lb_of(g) + u);
      const float* v = (net ? lv_v1 : mu_v1) + (size_t)j * Hh;
      float val[4][4]; float ss = 0.f;
      for (int ii = 0; ii < 4; ++ii)
        for (int t = 0; t < 4; ++t) {
          int kp = ii * 256 + 4 * l + t;
          float xx = v[p_of(kp)];
          val[ii][t] = xx; ss += xx * xx;
        }
      for (int s = 32; s; s >>= 1) ss += __shfl_xor(ss, s);
      float sc = ((net ? lv_g1 : mu_g1)[j]) * rsqrtf(ss);
      for (int ii = 0; ii < 4; ++ii) {
        int k0 = ii * 256 + 4 * l;
        u16x4 wv;
        for (int t = 0; t < 4; ++t)
          wv[t] = f2bf((g >= g_of(k0 + t)) ? sc * val[ii][t] : 0.f);
        int kt = k0 >> 6, kk = (k0 >> 5) & 1;
        int lanep = lane16 + 16 * ((k0 & 31) >> 3);
        *(u16x4*)(dstb + (size_t)(kt * 10 + nf * 2 + kk) * 512 +
                  lanep * 8 + (k0 & 7)) = wv;
      }
      if (l == 0) b1p[wid] = (net ? lv_b1 : mu_b1)[j];
    } else {
      u16x4 z = {0, 0, 0, 0};
      for (int ii = 0; ii < 4; ++ii) {
        int k0 = ii * 256 + 4 * l;
        int kt = k0 >> 6, kk = (k0 >> 5) & 1;
        int lanep = lane16 + 16 * ((k0 & 31) >> 3);
        *(u16x4*)(dstb + (size_t)(kt * 10 + nf * 2 + kk) * 512 +
                  lanep * 8 + (k0 & 7)) = z;
      }
      if (l == 0) b1p[wid] = 0.f;
    }
  }

  if (bid < 8) {  // W2p: one wave per (net, out-row)
    int wid2 = bid * 4 + w;                // 0..31
    int nn = wid2 >> 4, oi = wid2 & 15;
    const float* v = (nn ? lv_v2 : mu_v2) + (size_t)oi * Hh;
    float ss = 0.f;
    for (int ii = 0; ii < 4; ++ii) {
      f32x4 vv = *(const f32x4*)(v + ii * 256 + 4 * l);
      ss += vv[0]*vv[0] + vv[1]*vv[1] + vv[2]*vv[2] + vv[3]*vv[3];
    }
    for (int s = 32; s; s >>= 1) ss += __shfl_xor(ss, s);
    float sc = ((nn ? lv_g2 : mu_g2)[oi]) * rsqrtf(ss);
    for (int e = l; e < 15 * 104; e += 64) {
      int g = e / 104, u = e % 104;
      float val = 0.f;
      if (u < sz_of(g) && oi > g) val = sc * v[p_of(lb_of(g) + u)];
      W2p[nn * W2P_NET + g * (16 * 104) + oi * 104 + u] = f2bf(val);
    }
  }

  if (bid >= 8 && bid < 18) {  // W0p + b0p: one thread per padded unit
    int idx = (bid - 8) * 256 + tid;       // 0..2559
    if (idx < 2400) {
      int nn = idx / 1200, rem = idx % 1200;
      int g = rem / 80, u = rem % 80;
      u16* orow = W0p + nn * W0P_NET + g * (80 * 32) + u * 32;
      if (u < sz_of(g)) {
        int j = p_of(lb_of(g) + u);
        const float* v = (nn ? lv_v0 : mu_v0) + j * Dd;
        float vv[16]; float ss = 0.f;
        for (int k = 0; k < 16; ++k) { vv[k] = v[k]; ss += vv[k] * vv[k]; }
        float sc = ((nn ? lv_g0 : mu_g0)[j]) * rsqrtf(ss);
        for (int k = 0; k < 16; ++k)
          orow[k] = f2bf((g >= k) ? sc * vv[k] : 0.f);
        for (int k = 16; k < 32; ++k) orow[k] = 0;
        b0p[nn * 1200 + g * 80 + u] = (nn ? lv_b0 : mu_b0)[j];
      } else {
        for (int k = 0; k < 32; ++k) orow[k] = 0;
        b0p[nn * 1200 + g * 80 + u] = 0.f;
      }
    }
  }
}

// fragment load / mfma helper macros (all register indices compile-time)
#define LOADF(DST, BASE, KT)                                                \
  {                                                                         \
    const u16* fp_ = (BASE) + (size_t)(KT) * 5120;                          \
    _Pragma("unroll") for (int nf_ = 0; nf_ < 5; ++nf_)                     \
      _Pragma("unroll") for (int kk_ = 0; kk_ < 2; ++kk_)                   \
        DST[nf_][kk_] = *(const s16x8*)(fp_ + (nf_ * 2 + kk_) * 512);       \
  }
#define MFMAI(SLOT, KT)                                                     \
  {                                                                         \
    s16x8 a0_ = *(const s16x8*)(&h0L[net][lr][(KT) * 64 + lk * 8]);         \
    s16x8 a1_ = *(const s16x8*)(&h0L[net][lr][(KT) * 64 + 32 + lk * 8]);    \
    _Pragma("unroll") for (int nf_ = 0; nf_ < 5; ++nf_) {                   \
      hacc[nf_] = __builtin_amdgcn_mfma_f32_16x16x32_bf16(                  \
          a0_, SLOT[nf_][0], hacc[nf_], 0, 0, 0);                           \
      hacc[nf_] = __builtin_amdgcn_mfma_f32_16x16x32_bf16(                  \
          a1_, SLOT[nf_][1], hacc[nf_], 0, 0, 0);                           \
    }                                                                       \
  }

// --------------------------- main (one dispatch, 128 blocks) ---------------
__global__ __launch_bounds__(512, 1) void afmade_main(
    const u16* __restrict__ W1f, const u16* __restrict__ W2p,
    const u16* __restrict__ W0p,
    const float* __restrict__ b1p, const float* __restrict__ b0p,
    const float* __restrict__ b2_mu, const float* __restrict__ b2_lv,
    const float* __restrict__ x, float* __restrict__ out) {
  __shared__ u16 h0L[2][16][1040];        // stride 2080B (~4-way aliasing)
  __shared__ float sPart[2][4][16][80];   // 40 KB
  __shared__ u16 sH1[2][16][104];         // units 80..95 stay zero
  __shared__ u16 yb[16][40];              // cols 16..31 stay zero
  __shared__ float sX[16][16];
  __shared__ float sB1L[2400];
  __shared__ float sB0L[2400];
  __shared__ float sB2[2][16];
  __shared__ float sLsum[16];

  const int tid = threadIdx.x;
  const int l = tid & 63, w = tid >> 6;
  const int net = w >> 2, kq = w & 3;
  const int lr = l & 15, lk = l >> 4;
  const int b0g = blockIdx.x * 16;

  {  // zero-init LDS state (zeros make masked-weight products exact)
    u16x8 z = {0, 0, 0, 0, 0, 0, 0, 0};
    for (int e = tid; e < 4160; e += 512) ((u16x8*)h0L)[e] = z;
    for (int e = tid; e < 416; e += 512) ((u16x8*)sH1)[e] = z;
    for (int e = tid; e < 80; e += 512) ((u16x8*)yb)[e] = z;
  }
  for (int e = tid; e < 256; e += 512)
    sX[e >> 4][e & 15] = x[(size_t)(b0g + (e >> 4)) * 16 + (e & 15)];
  for (int e = tid; e < 2400; e += 512) { sB1L[e] = b1p[e]; sB0L[e] = b0p[e]; }
  if (tid < 16) sB2[0][tid] = b2_mu[tid];
  else if (tid < 32) sB2[1][tid - 16] = b2_lv[tid - 16];
  else if (tid < 48) sLsum[tid - 32] = 0.f;
  f32x4 mlacc0 = {0.f, 0.f, 0.f, 0.f};   // every wave: mu net ML (redundant)
  f32x4 mlacc1 = {0.f, 0.f, 0.f, 0.f};   // every wave: lv net ML (redundant)

  // 2-slot static register pipeline for W1 B-frags (R14-proven parity).
  s16x8 bfA[5][2], bfB[5][2];
  {  // prologue: step-1 (g=0, ktn=2) iter-0 -> A
    const u16* base1 = W1f + ((size_t)((net * 15 + 0) * 16) * 10) * 512 +
                       (size_t)l * 8;
    if (kq < 2) LOADF(bfA, base1, kq);
  }
  __syncthreads();

  for (int s = 0; s < 16; ++s) {
    // tiny W0 prefetch (consumed in tail; alive across lgkm-only barriers)
    s16x8 w0pre0, w0pre1;
    if (s < 15) {
      const u16* W0g = W0p + net * W0P_NET + s * (80 * 32);
      w0pre0 = *(const s16x8*)(W0g + (kq * 16 + lr) * 32 + lk * 8);
      if (kq == 0)
        w0pre1 = *(const s16x8*)(W0g + (64 + lr) * 32 + lk * 8);
    }

    if (s > 0) {
      const int g = s - 1;
      const int ktn = (lb_of(s) + 63) >> 6;
      const int ktnN = (s < 15) ? ((lb_of(s + 1) + 63) >> 6) : 0;
      const u16* baseg = W1f + ((size_t)((net * 15 + g) * 16) * 10) * 512 +
                         (size_t)l * 8;
      const u16* basen = W1f + ((size_t)((net * 15 + s) * 16) * 10) * 512 +
                         (size_t)l * 8;
      // ALL waves: issue both nets' W2 frag loads early (used after bar2)
      s16x8 w2f[6];
#pragma unroll
      for (int c = 0; c < 3; ++c) {
        w2f[c] = *(const s16x8*)(W2p + g * (16 * 104) + lr * 104 +
                                 c * 32 + lk * 8);
        w2f[3 + c] = *(const s16x8*)(W2p + W2P_NET + g * (16 * 104) +
                                     lr * 104 + c * 32 + lk * 8);
      }
      // GEMM, slots alternate A/B; i+1 prefetch issued at position i.
      f32x4 hacc[5] = {};
      if (kq + 4 < ktn)  LOADF(bfB, baseg, kq + 4);
      if (kq < ktn)      MFMAI(bfA, kq);
      if (kq + 8 < ktn)  LOADF(bfA, baseg, kq + 8);
      if (kq + 4 < ktn)  MFMAI(bfB, kq + 4);
      if (kq + 12 < ktn) LOADF(bfB, baseg, kq + 12);
      if (kq + 8 < ktn)  MFMAI(bfA, kq + 8);
      if (kq + 12 < ktn) MFMAI(bfB, kq + 12);
      // write partials
#pragma unroll
      for (int nf = 0; nf < 5; ++nf)
#pragma unroll
        for (int reg = 0; reg < 4; ++reg)
          sPart[net][kq][lk * 4 + reg][nf * 16 + lr] = hacc[nf][reg];
      // tail prefetch: next step's iter-0 lands under the step tail
      if (s < 15 && kq < ktnN) LOADF(bfA, basen, kq);
      barrier_lds();                       // bar1 (sPart visible)
      // reduce 4 partials + bias + elu -> sH1 (div-free mapping, 5/thread)
      {
        const int nn = tid >> 8;
        const int rr = (tid >> 4) & 15;
        const int u0 = tid & 15;
#pragma unroll
        for (int c = 0; c < 5; ++c) {
          int uu = c * 16 + u0;
          float v = sPart[nn][0][rr][uu] + sPart[nn][1][rr][uu] +
                    sPart[nn][2][rr][uu] + sPart[nn][3][rr][uu] +
                    sB1L[nn * 1200 + g * 80 + uu];
          sH1[nn][rr][uu] = f2bf(elu(v));
        }
      }
      barrier_lds();                       // bar2 (sH1 visible)
      // ML += h1grp @ W2g^T for BOTH nets, REDUNDANT in every wave
#pragma unroll
      for (int c = 0; c < 3; ++c) {
        s16x8 a0 = *(const s16x8*)(&sH1[0][lr][c * 32 + lk * 8]);
        mlacc0 = __builtin_amdgcn_mfma_f32_16x16x32_bf16(
            a0, w2f[c], mlacc0, 0, 0, 0);
        s16x8 a1v = *(const s16x8*)(&sH1[1][lr][c * 32 + lk * 8]);
        mlacc1 = __builtin_amdgcn_mfma_f32_16x16x32_bf16(
            a1v, w2f[3 + c], mlacc1, 0, 0, 0);
      }
    }
    // y update: EVERY wave computes y (lanes lr==s hold ML column s) and
    // writes yb (identical-value benign race). out/sLsum: wave 0 only
    // (sLsum is a read-modify-write -> single writer required).
    if (lr == s) {
#pragma unroll
      for (int reg = 0; reg < 4; ++reg) {
        int r = lk * 4 + reg;
        float mu = mlacc0[reg] + sB2[0][s];
        float lv = mlacc1[reg] + sB2[1][s];
        float ls = 0.5f * lv;
        float yv = (sX[r][s] - mu) / (__expf(ls) + EPSV);
        yb[r][s] = f2bf(yv);
        if (w == 0) {
          out[(size_t)(b0g + r) * 16 + s] = yv;
          float ns = sLsum[r] + ls;
          sLsum[r] = ns;
          if (s == 15) out[Bb * 16 + b0g + r] = ns;
        }
      }
    }
    // in-wave LDS ordering only: each wave wrote every yb row it reads.
    asm volatile("s_waitcnt lgkmcnt(0)" ::: "memory");
    if (s < 15) {
      // h0 group s = elu(y @ W0g^T + b0) -> h0L
      const int LbS = lb_of(s), szS = sz_of(s);
      s16x8 yfrag = *(const s16x8*)(&yb[lr][lk * 8]);
      {
        int unit = kq * 16 + lr;
        f32x4 h = __builtin_amdgcn_mfma_f32_16x16x32_bf16(
            yfrag, w0pre0, (f32x4){0.f, 0.f, 0.f, 0.f}, 0, 0, 0);
        if (unit < szS) {
          float bias = sB0L[net * 1200 + s * 80 + unit];
#pragma unroll
          for (int reg = 0; reg < 4; ++reg)
            h0L[net][lk * 4 + reg][LbS + unit] = f2bf(elu(h[reg] + bias));
        }
      }
      if (kq == 0) {
        int unit = 64 + lr;
        f32x4 h = __builtin_amdgcn_mfma_f32_16x16x32_bf16(
            yfrag, w0pre1, (f32x4){0.f, 0.f, 0.f, 0.f}, 0, 0, 0);
        if (unit < szS) {
          float bias = sB0L[net * 1200 + s * 80 + unit];
#pragma unroll
          for (int reg = 0; reg < 4; ++reg)
            h0L[net][lk * 4 + reg][LbS + unit] = f2bf(elu(h[reg] + bias));
        }
      }
      barrier_lds();                       // bar4 (h0L stable)
    }
  }
}

// --------------------------- launch ----------------------------------------

extern "C" void kernel_launch(void* const* d_in, const int* in_sizes, int n_in,
                              void* d_out, int out_size, void* d_ws, size_t ws_size,
                              hipStream_t stream) {
  const float* x     = (const float*)d_in[0];
  const float* mu_v0 = (const float*)d_in[1];
  const float* mu_g0 = (const float*)d_in[2];
  const float* mu_b0 = (const float*)d_in[3];
  const float* mu_v1 = (const float*)d_in[4];
  const float* mu_g1 = (const float*)d_in[5];
  const float* mu_b1 = (const float*)d_in[6];
  const float* mu_v2 = (const float*)d_in[7];
  const float* mu_g2 = (const float*)d_in[8];
  const float* mu_b2 = (const float*)d_in[9];
  const float* lv_v0 = (const float*)d_in[10];
  const float* lv_g0 = (const float*)d_in[11];
  const float* lv_b0 = (const float*)d_in[12];
  const float* lv_v1 = (const float*)d_in[13];
  const float* lv_g1 = (const float*)d_in[14];
  const float* lv_b1 = (const float*)d_in[15];
  const float* lv_v2 = (const float*)d_in[16];
  const float* lv_g2 = (const float*)d_in[17];
  const float* lv_b2 = (const float*)d_in[18];

  char* ws = (char*)d_ws;
  u16*   W1f = (u16*)(ws);                       // 4,915,200 B
  u16*   W2p = (u16*)(ws + 4915200);             //    99,840 B
  u16*   W0p = (u16*)(ws + 5015040);             //   153,600 B
  float* b1p = (float*)(ws + 5168640);           //     9,600 B
  float* b0p = (float*)(ws + 5178240);           //     9,600 B

  prep_all<<<600, 256, 0, stream>>>(
      mu_v0, mu_g0, mu_b0, mu_v1, mu_g1, mu_b1, mu_v2, mu_g2,
      lv_v0, lv_g0, lv_b0, lv_v1, lv_g1, lv_b1, lv_v2, lv_g2,
      W1f, W2p, W0p, b1p, b0p);

  afmade_main<<<128, 512, 0, stream>>>(W1f, W2p, W0p, b1p, b0p,
                                       mu_b2, lv_b2, x, (float*)d_out);
}

// Round 18
// 70.808 us; speedup vs baseline: 1.3368x; 1.0767x over previous
//
#include <hip/hip_runtime.h>
#include <cstdint>
#include <cstddef>

// ---------------------------------------------------------------------------
// AFMADE block, incremental-exact formulation. D=16, H=1024, B=2048.
// Degree-sorted space: y[d] final after step d; h0/h1 degree-groups computed
// once. Per step s: h1 group s-1 (K=Lb(s)) -> ML += @W2g -> mu/lv[s] ->
// y[s] -> h0 group s. Block owns 16 rows; 8 waves = (net, kq 4-way K-split).
// R18 = R17 + ALL weights baked in MFMA fragment order (W1f, W2f, W0f):
// every global load in the main loop is one contiguous 1KB wave-load.
// Redundant ML in all 8 waves (no bar3), 2-slot GEMM register pipeline,
// lgkmcnt-only barriers, 2 dispatches.
// ---------------------------------------------------------------------------

#define Dd 16
#define Hh 1024
#define Bb 2048
#define EPSV 1e-12f

typedef unsigned short u16;
typedef __attribute__((ext_vector_type(4))) float f32x4;
typedef __attribute__((ext_vector_type(8))) short s16x8;
typedef __attribute__((ext_vector_type(4))) u16 u16x4;
typedef __attribute__((ext_vector_type(8))) u16 u16x8;

__device__ __forceinline__ u16 f2bf(float f) {
  union { float f; unsigned u; } v; v.f = f;
  unsigned u = v.u;
  unsigned r = (u + 0x7fffu + ((u >> 16) & 1u)) >> 16;  // RNE
  return (u16)r;
}
__device__ __forceinline__ float elu(float a) {
  return a > 0.f ? a : __expf(a) - 1.f;
}
// LDS-visibility barrier that does NOT drain vmcnt (keeps prefetches alive).
__device__ __forceinline__ void barrier_lds() {
  asm volatile("s_waitcnt lgkmcnt(0)" ::: "memory");
  __builtin_amdgcn_s_barrier();
}

// Degree-sort permutation: group g = j%15; groups 0..3 have 69, 4..14 have 68.
__device__ __forceinline__ int p_of(int i) {
  if (i < 276) { int g = i / 69, q = i - g * 69; return g + 15 * q; }
  int r = i - 276; int g = 4 + r / 68, q = r - (g - 4) * 68;
  return g + 15 * q;
}
__device__ __forceinline__ int g_of(int i) {
  return (i < 276) ? (i / 69) : (4 + (i - 276) / 68);
}
__device__ __forceinline__ int lb_of(int g) {            // prefix length
  return (g <= 4) ? 69 * g : 276 + 68 * (g - 4);
}
__device__ __forceinline__ int sz_of(int g) { return (g < 4) ? 69 : 68; }

// Fragment layouts (all pads baked ZERO), lane l = (lr = l&15, lk = l>>4):
//  W1f[net][15 g][16 kt][5 nf][2 kk][64 l][8]  elem = W1[u=nf*16+lr][kt*64+kk*32+lk*8+t]
//  W2f[net][15 g][3 c][64 l][8]                elem = W2[oi=lr][c*32+lk*8+t] (K=96 pad 104->96 used)
//  W0f[net][15 g][5 nf][64 l][8]               elem = W0[u=nf*16+lr][lk*8+t] (K=32)
//  b1p/b0p[net][15][80] f32.
#define W2F_NET (15 * 3 * 512)
#define W0F_NET (15 * 5 * 512)

// --------------------------- prep (one dispatch, 600 blocks) ---------------
__global__ __launch_bounds__(256) void prep_all(
    const float* __restrict__ mu_v0, const float* __restrict__ mu_g0,
    const float* __restrict__ mu_b0,
    const float* __restrict__ mu_v1, const float* __restrict__ mu_g1,
    const float* __restrict__ mu_b1,
    const float* __restrict__ mu_v2, const float* __restrict__ mu_g2,
    const float* __restrict__ lv_v0, const float* __restrict__ lv_g0,
    const float* __restrict__ lv_b0,
    const float* __restrict__ lv_v1, const float* __restrict__ lv_g1,
    const float* __restrict__ lv_b1,
    const float* __restrict__ lv_v2, const float* __restrict__ lv_g2,
    u16* __restrict__ W1f, u16* __restrict__ W2f, u16* __restrict__ W0f,
    float* __restrict__ b1p, float* __restrict__ b0p) {
  int bid = blockIdx.x, tid = threadIdx.x;
  int l = tid & 63, w = tid >> 6;

  {  // W1f: one wave per padded row; wid = net*1200 + g*80 + u
    int wid = bid * 4 + w;                 // 0..2399
    int net = wid / 1200, rem = wid % 1200;
    int g = rem / 80, u = rem % 80;
    u16* dstb = W1f + ((size_t)((net * 15 + g) * 16) * 10) * 512;
    const int nf = u >> 4, lane16 = u & 15;
    if (u < sz_of(g)) {
      int j = p_of(lb_of(g) + u);
      const float* v = (net ? lv_v1 : mu_v1) + (size_t)j * Hh;
      float val[4][4]; float ss = 0.f;
      for (int ii = 0; ii < 4; ++ii)
        for (int t = 0; t < 4; ++t) {
          int kp = ii * 256 + 4 * l + t;
          float xx = v[p_of(kp)];
          val[ii][t] = xx; ss += xx * xx;
        }
      for (int s = 32; s; s >>= 1) ss += __shfl_xor(ss, s);
      float sc = ((net ? lv_g1 : mu_g1)[j]) * rsqrtf(ss);
      for (int ii = 0; ii < 4; ++ii) {
        int k0 = ii * 256 + 4 * l;
        u16x4 wv;
        for (int t = 0; t < 4; ++t)
          wv[t] = f2bf((g >= g_of(k0 + t)) ? sc * val[ii][t] : 0.f);
        int kt = k0 >> 6, kk = (k0 >> 5) & 1;
        int lanep = lane16 + 16 * ((k0 & 31) >> 3);
        *(u16x4*)(dstb + (size_t)(kt * 10 + nf * 2 + kk) * 512 +
                  lanep * 8 + (k0 & 7)) = wv;
      }
      if (l == 0) b1p[wid] = (net ? lv_b1 : mu_b1)[j];
    } else {
      u16x4 z = {0, 0, 0, 0};
      for (int ii = 0; ii < 4; ++ii) {
        int k0 = ii * 256 + 4 * l;
        int kt = k0 >> 6, kk = (k0 >> 5) & 1;
        int lanep = lane16 + 16 * ((k0 & 31) >> 3);
        *(u16x4*)(dstb + (size_t)(kt * 10 + nf * 2 + kk) * 512 +
                  lanep * 8 + (k0 & 7)) = z;
      }
      if (l == 0) b1p[wid] = 0.f;
    }
  }

  if (bid < 8) {  // W2f: one wave per (net, out-row oi); frag-order writes
    int wid2 = bid * 4 + w;                // 0..31
    int nn = wid2 >> 4, oi = wid2 & 15;
    const float* v = (nn ? lv_v2 : mu_v2) + (size_t)oi * Hh;
    float ss = 0.f;
    for (int ii = 0; ii < 4; ++ii) {
      f32x4 vv = *(const f32x4*)(v + ii * 256 + 4 * l);
      ss += vv[0]*vv[0] + vv[1]*vv[1] + vv[2]*vv[2] + vv[3]*vv[3];
    }
    for (int s = 32; s; s >>= 1) ss += __shfl_xor(ss, s);
    float sc = ((nn ? lv_g2 : mu_g2)[oi]) * rsqrtf(ss);
    // 15 g x 3 c x 4 lk = 180 u16x8 writes for this row
    for (int e = l; e < 180; e += 64) {
      int g = e / 12, r12 = e - g * 12;
      int c = r12 >> 2, lk2 = r12 & 3;
      u16x8 wv;
      for (int t = 0; t < 8; ++t) {
        int u = c * 32 + lk2 * 8 + t;      // 0..95
        float val = (u < sz_of(g) && oi > g) ? sc * v[p_of(lb_of(g) + u)]
                                             : 0.f;
        wv[t] = f2bf(val);
      }
      *(u16x8*)(W2f + (size_t)(nn * W2F_NET) + ((g * 3 + c) * 64 +
                (oi + 16 * lk2)) * 8) = wv;
    }
  }

  if (bid >= 8 && bid < 18) {  // W0f + b0p: one thread per padded unit
    int idx = (bid - 8) * 256 + tid;       // 0..2559
    if (idx < 2400) {
      int nn = idx / 1200, rem = idx % 1200;
      int g = rem / 80, u = rem % 80;
      const int nf = u >> 4, lr16 = u & 15;
      float row[16];
      float bias = 0.f;
      if (u < sz_of(g)) {
        int j = p_of(lb_of(g) + u);
        const float* v = (nn ? lv_v0 : mu_v0) + j * Dd;
        float vv[16]; float ss = 0.f;
        for (int k = 0; k < 16; ++k) { vv[k] = v[k]; ss += vv[k] * vv[k]; }
        float sc = ((nn ? lv_g0 : mu_g0)[j]) * rsqrtf(ss);
        for (int k = 0; k < 16; ++k) row[k] = (g >= k) ? sc * vv[k] : 0.f;
        bias = (nn ? lv_b0 : mu_b0)[j];
      } else {
        for (int k = 0; k < 16; ++k) row[k] = 0.f;
      }
      for (int lk2 = 0; lk2 < 4; ++lk2) {
        u16x8 wv;
        for (int t = 0; t < 8; ++t) {
          int k = lk2 * 8 + t;             // 0..31; cols 16..31 are zero
          wv[t] = f2bf((k < 16) ? row[k] : 0.f);
        }
        *(u16x8*)(W0f + (size_t)(nn * W0F_NET) + ((g * 5 + nf) * 64 +
                  (lr16 + 16 * lk2)) * 8) = wv;
      }
      b0p[nn * 1200 + g * 80 + u] = bias;
    }
  }
}

// fragment load / mfma helper macros (all register indices compile-time)
#define LOADF(DST, BASE, KT)                                                \
  {                                                                         \
    const u16* fp_ = (BASE) + (size_t)(KT) * 5120;                          \
    _Pragma("unroll") for (int nf_ = 0; nf_ < 5; ++nf_)                     \
      _Pragma("unroll") for (int kk_ = 0; kk_ < 2; ++kk_)                   \
        DST[nf_][kk_] = *(const s16x8*)(fp_ + (nf_ * 2 + kk_) * 512);       \
  }
#define MFMAI(SLOT, KT)                                                     \
  {                                                                         \
    s16x8 a0_ = *(const s16x8*)(&h0L[net][lr][(KT) * 64 + lk * 8]);         \
    s16x8 a1_ = *(const s16x8*)(&h0L[net][lr][(KT) * 64 + 32 + lk * 8]);    \
    _Pragma("unroll") for (int nf_ = 0; nf_ < 5; ++nf_) {                   \
      hacc[nf_] = __builtin_amdgcn_mfma_f32_16x16x32_bf16(                  \
          a0_, SLOT[nf_][0], hacc[nf_], 0, 0, 0);                           \
      hacc[nf_] = __builtin_amdgcn_mfma_f32_16x16x32_bf16(                  \
          a1_, SLOT[nf_][1], hacc[nf_], 0, 0, 0);                           \
    }                                                                       \
  }

// --------------------------- main (one dispatch, 128 blocks) ---------------
__global__ __launch_bounds__(512, 1) void afmade_main(
    const u16* __restrict__ W1f, const u16* __restrict__ W2f,
    const u16* __restrict__ W0f,
    const float* __restrict__ b1p, const float* __restrict__ b0p,
    const float* __restrict__ b2_mu, const float* __restrict__ b2_lv,
    const float* __restrict__ x, float* __restrict__ out) {
  __shared__ u16 h0L[2][16][1040];        // stride 2080B (~4-way aliasing)
  __shared__ float sPart[2][4][16][80];   // 40 KB
  __shared__ u16 sH1[2][16][104];         // units 80..95 stay zero
  __shared__ u16 yb[16][40];              // cols 16..31 stay zero
  __shared__ float sX[16][16];
  __shared__ float sB1L[2400];
  __shared__ float sB0L[2400];
  __shared__ float sB2[2][16];
  __shared__ float sLsum[16];

  const int tid = threadIdx.x;
  const int l = tid & 63, w = tid >> 6;
  const int net = w >> 2, kq = w & 3;
  const int lr = l & 15, lk = l >> 4;
  const int b0g = blockIdx.x * 16;

  {  // zero-init LDS state (zeros make masked-weight products exact)
    u16x8 z = {0, 0, 0, 0, 0, 0, 0, 0};
    for (int e = tid; e < 4160; e += 512) ((u16x8*)h0L)[e] = z;
    for (int e = tid; e < 416; e += 512) ((u16x8*)sH1)[e] = z;
    for (int e = tid; e < 80; e += 512) ((u16x8*)yb)[e] = z;
  }
  for (int e = tid; e < 256; e += 512)
    sX[e >> 4][e & 15] = x[(size_t)(b0g + (e >> 4)) * 16 + (e & 15)];
  for (int e = tid; e < 2400; e += 512) { sB1L[e] = b1p[e]; sB0L[e] = b0p[e]; }
  if (tid < 16) sB2[0][tid] = b2_mu[tid];
  else if (tid < 32) sB2[1][tid - 16] = b2_lv[tid - 16];
  else if (tid < 48) sLsum[tid - 32] = 0.f;
  f32x4 mlacc0 = {0.f, 0.f, 0.f, 0.f};   // every wave: mu net ML (redundant)
  f32x4 mlacc1 = {0.f, 0.f, 0.f, 0.f};   // every wave: lv net ML (redundant)

  // 2-slot static register pipeline for W1 B-frags (R14-proven parity).
  s16x8 bfA[5][2], bfB[5][2];
  {  // prologue: step-1 (g=0, ktn=2) iter-0 -> A
    const u16* base1 = W1f + ((size_t)((net * 15 + 0) * 16) * 10) * 512 +
                       (size_t)l * 8;
    if (kq < 2) LOADF(bfA, base1, kq);
  }
  __syncthreads();

  for (int s = 0; s < 16; ++s) {
    // W0 frag prefetch: contiguous 1KB loads (consumed in tail)
    s16x8 w0pre0, w0pre1;
    if (s < 15) {
      const u16* W0g = W0f + net * W0F_NET + s * (5 * 512);
      w0pre0 = *(const s16x8*)(W0g + (size_t)kq * 512 + l * 8);
      if (kq == 0)
        w0pre1 = *(const s16x8*)(W0g + (size_t)4 * 512 + l * 8);
    }

    if (s > 0) {
      const int g = s - 1;
      const int ktn = (lb_of(s) + 63) >> 6;
      const int ktnN = (s < 15) ? ((lb_of(s + 1) + 63) >> 6) : 0;
      const u16* baseg = W1f + ((size_t)((net * 15 + g) * 16) * 10) * 512 +
                         (size_t)l * 8;
      const u16* basen = W1f + ((size_t)((net * 15 + s) * 16) * 10) * 512 +
                         (size_t)l * 8;
      // ALL waves: both nets' W2 frag loads, contiguous (used after bar2)
      s16x8 w2f[6];
#pragma unroll
      for (int c = 0; c < 3; ++c) {
        w2f[c] = *(const s16x8*)(W2f + ((size_t)(g * 3 + c) * 64 + l) * 8);
        w2f[3 + c] = *(const s16x8*)(W2f + (size_t)W2F_NET +
                                     ((size_t)(g * 3 + c) * 64 + l) * 8);
      }
      // GEMM, slots alternate A/B; i+1 prefetch issued at position i.
      f32x4 hacc[5] = {};
      if (kq + 4 < ktn)  LOADF(bfB, baseg, kq + 4);
      if (kq < ktn)      MFMAI(bfA, kq);
      if (kq + 8 < ktn)  LOADF(bfA, baseg, kq + 8);
      if (kq + 4 < ktn)  MFMAI(bfB, kq + 4);
      if (kq + 12 < ktn) LOADF(bfB, baseg, kq + 12);
      if (kq + 8 < ktn)  MFMAI(bfA, kq + 8);
      if (kq + 12 < ktn) MFMAI(bfB, kq + 12);
      // write partials
#pragma unroll
      for (int nf = 0; nf < 5; ++nf)
#pragma unroll
        for (int reg = 0; reg < 4; ++reg)
          sPart[net][kq][lk * 4 + reg][nf * 16 + lr] = hacc[nf][reg];
      // tail prefetch: next step's iter-0 lands under the step tail
      if (s < 15 && kq < ktnN) LOADF(bfA, basen, kq);
      barrier_lds();                       // bar1 (sPart visible)
      // reduce 4 partials + bias + elu -> sH1 (div-free mapping, 5/thread)
      {
        const int nn = tid >> 8;
        const int rr = (tid >> 4) & 15;
        const int u0 = tid & 15;
#pragma unroll
        for (int c = 0; c < 5; ++c) {
          int uu = c * 16 + u0;
          float v = sPart[nn][0][rr][uu] + sPart[nn][1][rr][uu] +
                    sPart[nn][2][rr][uu] + sPart[nn][3][rr][uu] +
                    sB1L[nn * 1200 + g * 80 + uu];
          sH1[nn][rr][uu] = f2bf(elu(v));
        }
      }
      barrier_lds();                       // bar2 (sH1 visible)
      // ML += h1grp @ W2g^T for BOTH nets, REDUNDANT in every wave
#pragma unroll
      for (int c = 0; c < 3; ++c) {
        s16x8 a0 = *(const s16x8*)(&sH1[0][lr][c * 32 + lk * 8]);
        mlacc0 = __builtin_amdgcn_mfma_f32_16x16x32_bf16(
            a0, w2f[c], mlacc0, 0, 0, 0);
        s16x8 a1v = *(const s16x8*)(&sH1[1][lr][c * 32 + lk * 8]);
        mlacc1 = __builtin_amdgcn_mfma_f32_16x16x32_bf16(
            a1v, w2f[3 + c], mlacc1, 0, 0, 0);
      }
    }
    // y update: EVERY wave computes y (lanes lr==s hold ML column s) and
    // writes yb (identical-value benign race). out/sLsum: wave 0 only.
    if (lr == s) {
#pragma unroll
      for (int reg = 0; reg < 4; ++reg) {
        int r = lk * 4 + reg;
        float mu = mlacc0[reg] + sB2[0][s];
        float lv = mlacc1[reg] + sB2[1][s];
        float ls = 0.5f * lv;
        float yv = (sX[r][s] - mu) / (__expf(ls) + EPSV);
        yb[r][s] = f2bf(yv);
        if (w == 0) {
          out[(size_t)(b0g + r) * 16 + s] = yv;
          float ns = sLsum[r] + ls;
          sLsum[r] = ns;
          if (s == 15) out[Bb * 16 + b0g + r] = ns;
        }
      }
    }
    // in-wave LDS ordering only: each wave wrote every yb row it reads.
    asm volatile("s_waitcnt lgkmcnt(0)" ::: "memory");
    if (s < 15) {
      // h0 group s = elu(y @ W0g^T + b0) -> h0L
      const int LbS = lb_of(s), szS = sz_of(s);
      s16x8 yfrag = *(const s16x8*)(&yb[lr][lk * 8]);
      {
        int unit = kq * 16 + lr;
        f32x4 h = __builtin_amdgcn_mfma_f32_16x16x32_bf16(
            yfrag, w0pre0, (f32x4){0.f, 0.f, 0.f, 0.f}, 0, 0, 0);
        if (unit < szS) {
          float bias = sB0L[net * 1200 + s * 80 + unit];
#pragma unroll
          for (int reg = 0; reg < 4; ++reg)
            h0L[net][lk * 4 + reg][LbS + unit] = f2bf(elu(h[reg] + bias));
        }
      }
      if (kq == 0) {
        int unit = 64 + lr;
        f32x4 h = __builtin_amdgcn_mfma_f32_16x16x32_bf16(
            yfrag, w0pre1, (f32x4){0.f, 0.f, 0.f, 0.f}, 0, 0, 0);
        if (unit < szS) {
          float bias = sB0L[net * 1200 + s * 80 + unit];
#pragma unroll
          for (int reg = 0; reg < 4; ++reg)
            h0L[net][lk * 4 + reg][LbS + unit] = f2bf(elu(h[reg] + bias));
        }
      }
      barrier_lds();                       // bar4 (h0L stable)
    }
  }
}

// --------------------------- launch ----------------------------------------

extern "C" void kernel_launch(void* const* d_in, const int* in_sizes, int n_in,
                              void* d_out, int out_size, void* d_ws, size_t ws_size,
                              hipStream_t stream) {
  const float* x     = (const float*)d_in[0];
  const float* mu_v0 = (const float*)d_in[1];
  const float* mu_g0 = (const float*)d_in[2];
  const float* mu_b0 = (const float*)d_in[3];
  const float* mu_v1 = (const float*)d_in[4];
  const float* mu_g1 = (const float*)d_in[5];
  const float* mu_b1 = (const float*)d_in[6];
  const float* mu_v2 = (const float*)d_in[7];
  const float* mu_g2 = (const float*)d_in[8];
  const float* mu_b2 = (const float*)d_in[9];
  const float* lv_v0 = (const float*)d_in[10];
  const float* lv_g0 = (const float*)d_in[11];
  const float* lv_b0 = (const float*)d_in[12];
  const float* lv_v1 = (const float*)d_in[13];
  const float* lv_g1 = (const float*)d_in[14];
  const float* lv_b1 = (const float*)d_in[15];
  const float* lv_v2 = (const float*)d_in[16];
  const float* lv_g2 = (const float*)d_in[17];
  const float* lv_b2 = (const float*)d_in[18];

  char* ws = (char*)d_ws;
  u16*   W1f = (u16*)(ws);                       // 4,915,200 B
  u16*   W2f = (u16*)(ws + 4915200);             //    92,160 B
  u16*   W0f = (u16*)(ws + 5007360);             //   153,600 B
  float* b1p = (float*)(ws + 5160960);           //     9,600 B
  float* b0p = (float*)(ws + 5170560);           //     9,600 B

  prep_all<<<600, 256, 0, stream>>>(
      mu_v0, mu_g0, mu_b0, mu_v1, mu_g1, mu_b1, mu_v2, mu_g2,
      lv_v0, lv_g0, lv_b0, lv_v1, lv_g1, lv_b1, lv_v2, lv_g2,
      W1f, W2f, W0f, b1p, b0p);

  afmade_main<<<128, 512, 0, stream>>>(W1f, W2f, W0f, b1p, b0p,
                                       mu_b2, lv_b2, x, (float*)d_out);
}